// Round 10
// baseline (302.937 us; speedup 1.0000x reference)
//
#include <hip/hip_runtime.h>
#include <hip/hip_bf16.h>
#include <math.h>

// CrossPairMemory round 10: r9 config + ONE change: gemm_thin + ln_gelu fused
// into fused_mlp1 (16-row blocks, B streamed from L2, row-LN+GELU epilogue,
// writes h2 directly). hpreb buffer and 59MB of intermediate traffic removed.

#define B_SZ  4096
#define NPAIR 28
#define PDIM  128
#define MDIM  256
#define NSLOT 64
#define DALL  3584
#define DCAT  7168
#define KS2   16
#define KCH2  448   // DCAT / KS2
#define HCOLS 3600  // DALL + 16 pad (lk-rows -> +8 banks, conflict-free)

typedef __hip_bfloat16 bf16;
typedef __attribute__((ext_vector_type(8))) short bf16x8;
typedef __attribute__((ext_vector_type(4))) short short4v;
typedef __attribute__((ext_vector_type(4))) float f32x4;

#define BARRIER() asm volatile("s_barrier" ::: "memory")
#define LGKM0()   asm volatile("s_waitcnt lgkmcnt(0)" ::: "memory")
#define VMCNT4()  asm volatile("s_waitcnt vmcnt(4)" ::: "memory")
#define VMCNT0()  asm volatile("s_waitcnt vmcnt(0)" ::: "memory")

__device__ __forceinline__ void async_copy16(void* lds, const void* g) {
  __builtin_amdgcn_global_load_lds((__attribute__((address_space(1))) void*)g,
                                   (__attribute__((address_space(3))) void*)lds,
                                   16, 0, 0);
}

// ============== 256x224x64 2-phase GEMM (r6/r7/r9 schedule, 95us) ==========
__global__ __launch_bounds__(512, 2)
void gemm224(const bf16* __restrict__ A, const bf16* __restrict__ Bt,
             bf16* __restrict__ Cout, const float* __restrict__ bias) {
  __shared__ __align__(16) char smem[131072];
  const int tid = threadIdx.x;
  const int wid = tid >> 6, lane = tid & 63;
  const int lr = lane & 15, lk = lane >> 4;
  const int wm = wid >> 1, wn = wid & 1;
  const int swz = ((int)blockIdx.x & 7) * 32 + ((int)blockIdx.x >> 3);
  const int bx = swz & 15, by = swz >> 4;
  const int col0 = bx * 224, row0 = by * 256;

  char* sA = smem;
  char* sB = smem + 65536;

  const int srow = tid >> 3;
  const int sg = (tid & 7) ^ (srow & 7);
  const bf16* aStage = A + (long)(row0 + srow) * DALL + sg * 8;
  const bf16* bStage = Bt + (long)(col0 + srow) * DALL + sg * 8;
  const int wOff = wid << 10;

  const int NT = DALL >> 6;  // 56

  const int sx = lr & 7;
  const int arowb = wm * 64 + lr;
  const int browb = wn * 112 + lr;

  f32x4 acc[4][7];
  const f32x4 zero = {0.f, 0.f, 0.f, 0.f};
#pragma unroll
  for (int m = 0; m < 4; ++m)
#pragma unroll
    for (int n = 0; n < 7; ++n) acc[m][n] = zero;

#pragma unroll
  for (int i = 0; i < 4; ++i)
    async_copy16(sB + i * 8192 + wOff, bStage + (long)i * 64 * DALL);
#pragma unroll
  for (int i = 0; i < 4; ++i)
    async_copy16(sA + i * 8192 + wOff, aStage + (long)i * 64 * DALL);
#pragma unroll
  for (int i = 0; i < 4; ++i)
    async_copy16(sB + 32768 + i * 8192 + wOff, bStage + (long)i * 64 * DALL + 64);
  VMCNT4();
  BARRIER();

  bf16x8 af[4][2], bf[7][2];

  for (int t = 0; t < NT; ++t) {
    const int cur = t & 1;
    char* cA = sA + cur * 32768;
    char* cB = sB + cur * 32768;
    char* nA = sA + (cur ^ 1) * 32768;

    if (t + 1 < NT) {
      const bf16* g = aStage + (long)(t + 1) * 64;
#pragma unroll
      for (int i = 0; i < 4; ++i)
        async_copy16(nA + i * 8192 + wOff, g + (long)i * 64 * DALL);
    }
#pragma unroll
    for (int m = 0; m < 4; ++m)
#pragma unroll
      for (int kk = 0; kk < 2; ++kk)
        af[m][kk] = *(const bf16x8*)(cA + (arowb + m * 16) * 128 +
                                     ((((kk << 2) | lk) ^ sx) << 4));
#pragma unroll
    for (int n = 0; n < 7; ++n)
#pragma unroll
      for (int kk = 0; kk < 2; ++kk)
        bf[n][kk] = *(const bf16x8*)(cB + (browb + n * 16) * 128 +
                                     ((((kk << 2) | lk) ^ sx) << 4));
    __builtin_amdgcn_s_setprio(1);
#pragma unroll
    for (int m = 0; m < 4; ++m)
#pragma unroll
      for (int n = 0; n < 4; ++n)
#pragma unroll
        for (int kk = 0; kk < 2; ++kk)
          acc[m][n] = __builtin_amdgcn_mfma_f32_16x16x32_bf16(
              af[m][kk], bf[n][kk], acc[m][n], 0, 0, 0);
    __builtin_amdgcn_s_setprio(0);
    LGKM0();
    BARRIER();

    const int more = (t + 2 < NT);
    if (more) {
      const bf16* g = bStage + (long)(t + 2) * 64;
#pragma unroll
      for (int i = 0; i < 4; ++i)
        async_copy16(cB + i * 8192 + wOff, g + (long)i * 64 * DALL);
    }
    __builtin_amdgcn_s_setprio(1);
#pragma unroll
    for (int m = 0; m < 4; ++m)
#pragma unroll
      for (int n = 4; n < 7; ++n)
#pragma unroll
        for (int kk = 0; kk < 2; ++kk)
          acc[m][n] = __builtin_amdgcn_mfma_f32_16x16x32_bf16(
              af[m][kk], bf[n][kk], acc[m][n], 0, 0, 0);
    __builtin_amdgcn_s_setprio(0);
    if (more) { VMCNT4(); } else { VMCNT0(); }
    BARRIER();
  }

#pragma unroll
  for (int m = 0; m < 4; ++m) {
#pragma unroll
    for (int n = 0; n < 7; ++n) {
      const int gc = col0 + wn * 112 + n * 16 + lr;
      const float bia = bias[gc];
#pragma unroll
      for (int j = 0; j < 4; ++j) {
        const int gr = row0 + wm * 64 + m * 16 + lk * 4 + j;
        Cout[(long)gr * DALL + gc] = __float2bfloat16(acc[m][n][j] + bia);
      }
    }
  }
}

// ---------------- transpose + fp32->bf16 convert, short4 writes (r7) -------
__global__ __launch_bounds__(256)
void tconv_kernel(const float* __restrict__ in, bf16* __restrict__ out,
                  int R, int C, int inBatch, int outBatch) {
  __shared__ float tile[32][33];
  const int tid = threadIdx.x;
  const int tx = tid & 31, ty = tid >> 5;
  const long ib = (long)blockIdx.z * inBatch;
  const long ob = (long)blockIdx.z * outBatch;
  const int c0 = blockIdx.x * 32, r0 = blockIdx.y * 32;
#pragma unroll
  for (int i = 0; i < 4; ++i)
    tile[ty + i * 8][tx] = in[ib + (long)(r0 + ty + i * 8) * C + c0 + tx];
  __syncthreads();
  const int cl = tid >> 3, rq = (tid & 7) * 4;
  union { bf16 h[4]; short4v v; } u;
#pragma unroll
  for (int j = 0; j < 4; ++j) u.h[j] = __float2bfloat16(tile[rq + j][cl]);
  *(short4v*)(out + ob + (long)(c0 + cl) * R + r0 + rq) = u.v;
}

// ---------------- fp32->bf16 convert for pair_vals + macro_vals (r7) -------
__global__ __launch_bounds__(256)
void conv2_kernel(const float* __restrict__ pv, const float* __restrict__ mv,
                  bf16* __restrict__ pvb, bf16* __restrict__ mvb) {
  const float* in = blockIdx.y ? mv : pv;
  bf16* out = blockIdx.y ? mvb : pvb;
  const int i = (blockIdx.x * 256 + threadIdx.x) * 8;
  float4 a = *(const float4*)(in + i);
  float4 b = *(const float4*)(in + i + 4);
  union { bf16 h[8]; bf16x8 v; } u;
  u.h[0] = __float2bfloat16(a.x); u.h[1] = __float2bfloat16(a.y);
  u.h[2] = __float2bfloat16(a.z); u.h[3] = __float2bfloat16(a.w);
  u.h[4] = __float2bfloat16(b.x); u.h[5] = __float2bfloat16(b.y);
  u.h[6] = __float2bfloat16(b.z); u.h[7] = __float2bfloat16(b.w);
  *(bf16x8*)(out + i) = u.v;
}

// ---------------- prep: single-pass convert + fused pair-mean (r9) ---------
__global__ __launch_bounds__(256)
void prep_kernel(const float* __restrict__ ps, const float* __restrict__ mac,
                 const float* __restrict__ pkeys, const float* __restrict__ mkeys,
                 bf16* __restrict__ psb, bf16* __restrict__ att) {
  const int b = blockIdx.x, tid = threadIdx.x;
  __shared__ float q[PDIM];
  __shared__ float mrow[MDIM];
  __shared__ float red[16][PDIM];
  const float* prow = ps + (long)b * DALL;
  if (tid < MDIM) mrow[tid] = mac[(long)b * MDIM + tid];
  float a8[8];
#pragma unroll
  for (int j = 0; j < 8; ++j) a8[j] = 0.f;
  for (int i = tid * 8; i < DALL; i += 2048) {
    float4 a = *(const float4*)(prow + i);
    float4 c = *(const float4*)(prow + i + 4);
    union { bf16 h[8]; bf16x8 v; } u;
    u.h[0] = __float2bfloat16(a.x); u.h[1] = __float2bfloat16(a.y);
    u.h[2] = __float2bfloat16(a.z); u.h[3] = __float2bfloat16(a.w);
    u.h[4] = __float2bfloat16(c.x); u.h[5] = __float2bfloat16(c.y);
    u.h[6] = __float2bfloat16(c.z); u.h[7] = __float2bfloat16(c.w);
    *(bf16x8*)(psb + (long)b * DALL + i) = u.v;
    a8[0] += a.x; a8[1] += a.y; a8[2] += a.z; a8[3] += a.w;
    a8[4] += c.x; a8[5] += c.y; a8[6] += c.z; a8[7] += c.w;
  }
  {
    float* rp = &red[tid >> 4][(tid & 15) * 8];
    *(f32x4*)rp = *(f32x4*)&a8[0];
    *(f32x4*)(rp + 4) = *(f32x4*)&a8[4];
  }
  __syncthreads();
  if (tid < PDIM) {
    float s = 0.f;
#pragma unroll
    for (int k = 0; k < 16; ++k) s += red[k][tid];
    q[tid] = s * (1.f / NPAIR);
  }
  __syncthreads();
  const int wid = tid >> 6, lane = tid & 63;
  if (wid == 0) {
    float sc = 0.f;
    const float* kr = pkeys + lane * PDIM;
    for (int d = 0; d < PDIM; ++d) sc += q[d] * kr[d];
    sc *= 0.08838834764831845f;
    float mx = sc;
#pragma unroll
    for (int m = 32; m; m >>= 1) mx = fmaxf(mx, __shfl_xor(mx, m));
    float e = expf(sc - mx);
    float ssum = e;
#pragma unroll
    for (int m = 32; m; m >>= 1) ssum += __shfl_xor(ssum, m);
    att[(long)b * 128 + lane] = __float2bfloat16(e / ssum);
  } else if (wid == 1) {
    float sc = 0.f;
    const float* kr = mkeys + lane * MDIM;
    for (int d = 0; d < MDIM; ++d) sc += mrow[d] * kr[d];
    sc *= 0.0625f;
    float mx = sc;
#pragma unroll
    for (int m = 32; m; m >>= 1) mx = fmaxf(mx, __shfl_xor(mx, m));
    float e = expf(sc - mx);
    float ssum = e;
#pragma unroll
    for (int m = 32; m; m >>= 1) ssum += __shfl_xor(ssum, m);
    att[(long)b * 128 + 64 + lane] = __float2bfloat16(e / ssum);
  }
}

// ---------------- CVt precompute DIRECT from fp32 w1 (r7, verified) --------
__global__ __launch_bounds__(256)
void precompute_direct(const float* __restrict__ w1, const bf16* __restrict__ pvb,
                       const bf16* __restrict__ mvb, float* __restrict__ part) {
  __shared__ __align__(16) bf16 sAt[256 * 40];
  __shared__ __align__(16) bf16 sBt[64 * 32];
  const int tid = threadIdx.x, wid = tid >> 6, lane = tid & 63;
  const int lr = lane & 15, lk = lane >> 4;
  const int n0 = blockIdx.x * 256;
  const int ksb = blockIdx.y;
  const int kbase = ksb * KCH2;
  const bf16* vb = (ksb < 8) ? pvb : mvb;
  const int kcol0 = (ksb < 8) ? kbase : kbase - DALL;

  const int bs = tid >> 2;
  const int bgs = (tid & 3) ^ (bs & 3);

  f32x4 acc[4][4];
  const f32x4 zero = {0.f, 0.f, 0.f, 0.f};
#pragma unroll
  for (int m = 0; m < 4; ++m)
#pragma unroll
    for (int n = 0; n < 4; ++n) acc[m][n] = zero;

  for (int kt = 0; kt < KCH2; kt += 32) {
    __syncthreads();
    {
      const float* src = w1 + (long)(kbase + kt) * DALL + n0 + tid;
      bf16* dst = sAt + tid * 40;
#pragma unroll
      for (int r8 = 0; r8 < 32; r8 += 4) {
        union { bf16 h[4]; short4v v; } u;
#pragma unroll
        for (int j = 0; j < 4; ++j)
          u.h[j] = __float2bfloat16(src[(long)(r8 + j) * DALL]);
        *(short4v*)(dst + r8) = u.v;
      }
    }
    async_copy16((char*)sBt + tid * 16,
                 vb + (long)bs * DALL + kcol0 + kt + bgs * 8);
    __syncthreads();
    bf16x8 af[4], bfr[4];
#pragma unroll
    for (int m = 0; m < 4; ++m)
      af[m] = *(const bf16x8*)((const char*)sAt +
                               ((wid * 64 + m * 16 + lr) * 40 + lk * 8) * 2);
#pragma unroll
    for (int n = 0; n < 4; ++n) {
      const int s = n * 16 + lr;
      bfr[n] = *(const bf16x8*)((const char*)sBt + s * 64 + ((lk ^ (s & 3)) << 4));
    }
#pragma unroll
    for (int m = 0; m < 4; ++m)
#pragma unroll
      for (int n = 0; n < 4; ++n)
        acc[m][n] =
            __builtin_amdgcn_mfma_f32_16x16x32_bf16(af[m], bfr[n], acc[m][n], 0, 0, 0);
  }
#pragma unroll
  for (int m = 0; m < 4; ++m)
#pragma unroll
    for (int n = 0; n < 4; ++n)
#pragma unroll
      for (int j = 0; j < 4; ++j) {
        const int gn = n0 + wid * 64 + m * 16 + lk * 4 + j;
        const int s = n * 16 + lr;
        part[((long)ksb * DALL + gn) * 64 + s] = acc[m][n][j];
      }
}

// ---------------- reduce K-split partials -> CVt bf16 [3584][128] ----------
__global__ __launch_bounds__(256)
void reduce_cvt(const float* __restrict__ part, bf16* __restrict__ cvt) {
  const long i4 = ((long)blockIdx.x * 256 + threadIdx.x) * 4;
  const int n = (int)(i4 >> 7), sc = (int)(i4 & 127);
  const int half = sc >> 6, s0 = sc & 63;
  f32x4 s = {0.f, 0.f, 0.f, 0.f};
#pragma unroll
  for (int j = 0; j < 8; ++j)
    s += *(const f32x4*)(part + ((long)(half * 8 + j) * DALL + n) * 64 + s0);
#pragma unroll
  for (int k = 0; k < 4; ++k) cvt[i4 + k] = __float2bfloat16(s[k]);
}

// ---------------- fused: h2 = gelu(LN(att @ cvt^T + b1)) -------------------
// 16 rows/block, grid 256 (1 block/CU). K=128. B streamed global->VGPR (cvt
// is 896KB, L2-resident). Per wave: 896-col slice in 2 halves of 28 f32x4
// acc. Epilogue: bias -> f32 row stats (shfl over lr + LDS cross-wave) ->
// stage h bf16 to padded LDS [16][3600] -> coalesced LN+GELU apply -> h2.
__global__ __launch_bounds__(256)
void fused_mlp1(const bf16* __restrict__ att, const bf16* __restrict__ cvt,
                const float* __restrict__ b1, const float* __restrict__ g,
                const float* __restrict__ bb, bf16* __restrict__ h2) {
  __shared__ __align__(16) bf16 sH[16 * HCOLS];   // 115.2 KB
  __shared__ float sred[4][16][2];
  const int tid = threadIdx.x, wid = tid >> 6, lane = tid & 63;
  const int lr = lane & 15, lk = lane >> 4;
  const int r0 = blockIdx.x * 16;
  const int c0 = wid * 896;

  // A frags: rows r0+lr, k = ks*32 + lk*8
  bf16x8 af[4];
#pragma unroll
  for (int ks = 0; ks < 4; ++ks)
    af[ks] = *(const bf16x8*)(att + (long)(r0 + lr) * 128 + ks * 32 + lk * 8);

  float s1[4], s2[4];
#pragma unroll
  for (int j = 0; j < 4; ++j) { s1[j] = 0.f; s2[j] = 0.f; }

  const f32x4 zero = {0.f, 0.f, 0.f, 0.f};
#pragma unroll
  for (int half = 0; half < 2; ++half) {
    const int hc0 = c0 + half * 448;
    f32x4 acc[28];
#pragma unroll
    for (int n = 0; n < 28; ++n) acc[n] = zero;
#pragma unroll
    for (int ks = 0; ks < 4; ++ks)
#pragma unroll
      for (int n = 0; n < 28; ++n) {
        bf16x8 bfr = *(const bf16x8*)(cvt + (long)(hc0 + n * 16 + lr) * 128 +
                                      ks * 32 + lk * 8);
        acc[n] = __builtin_amdgcn_mfma_f32_16x16x32_bf16(af[ks], bfr, acc[n], 0, 0, 0);
      }
    // bias + stats + stage
#pragma unroll
    for (int n = 0; n < 28; ++n) {
      const int col = hc0 + n * 16 + lr;
      const float bia = b1[col];
#pragma unroll
      for (int j = 0; j < 4; ++j) {
        const float v = acc[n][j] + bia;
        s1[j] += v;
        s2[j] += v * v;
        sH[(lk * 4 + j) * HCOLS + col] = __float2bfloat16(v);
      }
    }
  }
  // reduce over lr lanes (masks 1,2,4,8 stay within the 16-lane lr group)
#pragma unroll
  for (int j = 0; j < 4; ++j) {
#pragma unroll
    for (int msk = 1; msk <= 8; msk <<= 1) {
      s1[j] += __shfl_xor(s1[j], msk);
      s2[j] += __shfl_xor(s2[j], msk);
    }
  }
  if (lr == 0) {
#pragma unroll
    for (int j = 0; j < 4; ++j) {
      sred[wid][lk * 4 + j][0] = s1[j];
      sred[wid][lk * 4 + j][1] = s2[j];
    }
  }
  __syncthreads();
  // apply: thread -> row tid>>4, cols (tid&15)*8 + 128*c
  const int row = tid >> 4, cb = (tid & 15) * 8;
  float t1 = 0.f, t2 = 0.f;
#pragma unroll
  for (int w = 0; w < 4; ++w) { t1 += sred[w][row][0]; t2 += sred[w][row][1]; }
  const float mean = t1 * (1.f / DALL);
  const float var = t2 * (1.f / DALL) - mean * mean;
  const float rstd = rsqrtf(var + 1e-5f);
  bf16* orow = h2 + (long)(r0 + row) * DALL;
#pragma unroll
  for (int c = cb; c < DALL; c += 128) {
    bf16x8 hv = *(const bf16x8*)(sH + row * HCOLS + c);
    float4 g0 = *(const float4*)(g + c);
    float4 g1 = *(const float4*)(g + c + 4);
    float4 b0 = *(const float4*)(bb + c);
    float4 b1v = *(const float4*)(bb + c + 4);
    const float gg[8] = {g0.x, g0.y, g0.z, g0.w, g1.x, g1.y, g1.z, g1.w};
    const float bbv[8] = {b0.x, b0.y, b0.z, b0.w, b1v.x, b1v.y, b1v.z, b1v.w};
    union { bf16 hh[8]; bf16x8 vv; } u;
#pragma unroll
    for (int j = 0; j < 8; ++j) {
      const float x = __bfloat162float(((const bf16*)&hv)[j]);
      const float y = (x - mean) * rstd * gg[j] + bbv[j];
      u.hh[j] = __float2bfloat16(0.5f * y * (1.f + erff(y * 0.7071067811865475f)));
    }
    *(bf16x8*)(orow + c) = u.vv;
  }
}

// ---------------- per-pair GEMM (K=256, BK=64 swizzled) + LN (r7) ----------
__global__ __launch_bounds__(256)
void pair_final(const bf16* __restrict__ psb, const bf16* __restrict__ fusedb,
                const bf16* __restrict__ pwT, const float* __restrict__ pb,
                const float* __restrict__ lng, const float* __restrict__ lnb,
                float* __restrict__ out) {
  __shared__ __align__(16) bf16 sA[128 * 64];
  __shared__ __align__(16) bf16 sB[128 * 64];
  const int tid = threadIdx.x, wid = tid >> 6, lane = tid & 63;
  const int lr = lane & 15, lk = lane >> 4;
  const int p = blockIdx.y, row0 = blockIdx.x * 128;
  const int srl = lane >> 3;
  const int sgl = (lane & 7) ^ srl;
  const int sx = lr & 7;
  const bf16* pwp = pwT + (long)p * (PDIM * MDIM);

  f32x4 acc[2][8];
  const f32x4 zero = {0.f, 0.f, 0.f, 0.f};
#pragma unroll
  for (int m = 0; m < 2; ++m)
#pragma unroll
    for (int n = 0; n < 8; ++n) acc[m][n] = zero;

  for (int kt = 0; kt < 4; ++kt) {
    __syncthreads();
    const bf16* Asrc = (kt < 2) ? psb : fusedb;
    const int acol = p * PDIM + (kt & 1) * 64;
#pragma unroll
    for (int i = 0; i < 4; ++i) {
      const int r = i * 32 + wid * 8 + srl;
      async_copy16((char*)sA + i * 4096 + wid * 1024,
                   Asrc + (long)(row0 + r) * DALL + acol + sgl * 8);
      async_copy16((char*)sB + i * 4096 + wid * 1024,
                   pwp + (long)r * MDIM + kt * 64 + sgl * 8);
    }
    __syncthreads();
#pragma unroll
    for (int kk = 0; kk < 2; ++kk) {
      bf16x8 a0[2], b0[8];
      const int gb = (((kk << 2) | lk) ^ sx) << 4;
#pragma unroll
      for (int m = 0; m < 2; ++m)
        a0[m] = *(const bf16x8*)((const char*)sA + (wid * 32 + m * 16 + lr) * 128 + gb);
#pragma unroll
      for (int n = 0; n < 8; ++n)
        b0[n] = *(const bf16x8*)((const char*)sB + (n * 16 + lr) * 128 + gb);
#pragma unroll
      for (int m = 0; m < 2; ++m)
#pragma unroll
        for (int n = 0; n < 8; ++n)
          acc[m][n] = __builtin_amdgcn_mfma_f32_16x16x32_bf16(
              a0[m], b0[n], acc[m][n], 0, 0, 0);
    }
  }
  float g_[8], b_[8], pb_[8];
#pragma unroll
  for (int n = 0; n < 8; ++n) {
    const int c = n * 16 + lr;
    g_[n] = lng[p * PDIM + c];
    b_[n] = lnb[p * PDIM + c];
    pb_[n] = pb[p * PDIM + c];
  }
#pragma unroll
  for (int m = 0; m < 2; ++m) {
#pragma unroll
    for (int j = 0; j < 4; ++j) {
      float vv[8];
      float s1 = 0.f, s2 = 0.f;
#pragma unroll
      for (int n = 0; n < 8; ++n) {
        vv[n] = acc[m][n][j] + pb_[n];
        s1 += vv[n];
        s2 += vv[n] * vv[n];
      }
#pragma unroll
      for (int msk = 1; msk <= 8; msk <<= 1) {
        s1 += __shfl_xor(s1, msk);
        s2 += __shfl_xor(s2, msk);
      }
      const float mean = s1 * (1.f / 128.f);
      const float var = s2 * (1.f / 128.f) - mean * mean;
      const float rstd = rsqrtf(var + 1e-5f);
      const int gr = row0 + wid * 32 + m * 16 + lk * 4 + j;
      float* orow = out + ((long)gr * NPAIR + p) * PDIM;
#pragma unroll
      for (int n = 0; n < 8; ++n)
        orow[n * 16 + lr] = (vv[n] - mean) * rstd * g_[n] + b_[n];
    }
  }
}

// ---------------------------------------------------------------------------
extern "C" void kernel_launch(void* const* d_in, const int* in_sizes, int n_in,
                              void* d_out, int out_size, void* d_ws, size_t ws_size,
                              hipStream_t stream) {
  (void)in_sizes; (void)n_in; (void)out_size; (void)ws_size;
  const float* ps   = (const float*)d_in[0];
  const float* mac  = (const float*)d_in[1];
  const float* pkey = (const float*)d_in[2];
  const float* pval = (const float*)d_in[3];
  const float* mkey = (const float*)d_in[4];
  const float* mval = (const float*)d_in[5];
  const float* w1   = (const float*)d_in[6];
  const float* b1   = (const float*)d_in[7];
  const float* lng1 = (const float*)d_in[8];
  const float* lnb1 = (const float*)d_in[9];
  const float* w2   = (const float*)d_in[10];
  const float* b2   = (const float*)d_in[11];
  const float* pw   = (const float*)d_in[12];
  const float* pb   = (const float*)d_in[13];
  const float* plng = (const float*)d_in[14];
  const float* plnb = (const float*)d_in[15];
  float* out = (float*)d_out;

  char* w = (char*)d_ws;
  size_t off = 0;
  auto carve = [&](size_t bytes) {
    char* pp = w + off;
    off += (bytes + 255) & ~(size_t)255;
    return pp;
  };
  bf16* psb   = (bf16*)carve((size_t)B_SZ * DALL * 2);
  bf16* w2t   = (bf16*)carve((size_t)(DALL + 32) * DALL * 2);  // +32 pad rows
  bf16* pvb   = (bf16*)carve((size_t)NSLOT * DALL * 2);
  bf16* mvb   = (bf16*)carve((size_t)NSLOT * DALL * 2);
  bf16* pwTb  = (bf16*)carve((size_t)NPAIR * PDIM * MDIM * 2);
  bf16* att   = (bf16*)carve((size_t)B_SZ * 128 * 2);
  bf16* cvt   = (bf16*)carve((size_t)DALL * 128 * 2);
  float* part = (float*)carve((size_t)KS2 * DALL * 64 * 4);
  bf16* h2    = (bf16*)carve((size_t)B_SZ * DALL * 2);
  bf16* fusedb = (bf16*)carve((size_t)B_SZ * DALL * 2);

  conv2_kernel<<<dim3(NSLOT * DALL / 2048, 2), 256, 0, stream>>>(pval, mval, pvb, mvb);
  tconv_kernel<<<dim3(DALL / 32, DALL / 32, 1), 256, 0, stream>>>(w2, w2t, DALL, DALL, 0, 0);
  tconv_kernel<<<dim3(PDIM / 32, MDIM / 32, NPAIR), 256, 0, stream>>>(
      pw, pwTb, MDIM, PDIM, MDIM * PDIM, MDIM * PDIM);
  prep_kernel<<<dim3(B_SZ), 256, 0, stream>>>(ps, mac, pkey, mkey, psb, att);
  precompute_direct<<<dim3(DALL / 256, KS2), 256, 0, stream>>>(w1, pvb, mvb, part);
  reduce_cvt<<<dim3(DALL * 128 / 1024), 256, 0, stream>>>(part, cvt);
  // fused: h2 = gelu(LN(att @ cvt^T + b1))  [hpreb + ln_gelu eliminated]
  fused_mlp1<<<dim3(B_SZ / 16), 256, 0, stream>>>(att, cvt, b1, lng1, lnb1, h2);
  gemm224<<<dim3(256), 512, 0, stream>>>(h2, w2t, fusedb, b2);
  pair_final<<<dim3(B_SZ / 128, NPAIR), 256, 0, stream>>>(
      psb, fusedb, pwTb, pb, plng, plnb, out);
}

// Round 11
// 275.031 us; speedup vs baseline: 1.1015x; 1.1015x over previous
//
#include <hip/hip_runtime.h>
#include <hip/hip_bf16.h>
#include <math.h>

// CrossPairMemory round 11: exact r9 revert (280.3us verified) + ONE change:
// conv2 + tconv_pw + tconv_w2 merged into a single flat-grid kernel
// (identical inner code per branch, uniform per-block branching) -> 2 fewer
// launches. No inner-loop, layout, or schedule changes anywhere.

#define B_SZ  4096
#define NPAIR 28
#define PDIM  128
#define MDIM  256
#define NSLOT 64
#define DALL  3584
#define DCAT  7168
#define KS2   16
#define KCH2  448   // DCAT / KS2

typedef __hip_bfloat16 bf16;
typedef __attribute__((ext_vector_type(8))) short bf16x8;
typedef __attribute__((ext_vector_type(4))) short short4v;
typedef __attribute__((ext_vector_type(4))) float f32x4;

#define BARRIER() asm volatile("s_barrier" ::: "memory")
#define LGKM0()   asm volatile("s_waitcnt lgkmcnt(0)" ::: "memory")
#define VMCNT4()  asm volatile("s_waitcnt vmcnt(4)" ::: "memory")
#define VMCNT0()  asm volatile("s_waitcnt vmcnt(0)" ::: "memory")

__device__ __forceinline__ void async_copy16(void* lds, const void* g) {
  __builtin_amdgcn_global_load_lds((__attribute__((address_space(1))) void*)g,
                                   (__attribute__((address_space(3))) void*)lds,
                                   16, 0, 0);
}

// ============== 256x224x64 2-phase GEMM (r6/r9 schedule+swizzle, 95us) =====
__global__ __launch_bounds__(512, 2)
void gemm224(const bf16* __restrict__ A, const bf16* __restrict__ Bt,
             bf16* __restrict__ Cout, const float* __restrict__ bias) {
  __shared__ __align__(16) char smem[131072];
  const int tid = threadIdx.x;
  const int wid = tid >> 6, lane = tid & 63;
  const int lr = lane & 15, lk = lane >> 4;
  const int wm = wid >> 1, wn = wid & 1;
  const int swz = ((int)blockIdx.x & 7) * 32 + ((int)blockIdx.x >> 3);
  const int bx = swz & 15, by = swz >> 4;
  const int col0 = bx * 224, row0 = by * 256;

  char* sA = smem;
  char* sB = smem + 65536;

  const int srow = tid >> 3;
  const int sg = (tid & 7) ^ (srow & 7);
  const bf16* aStage = A + (long)(row0 + srow) * DALL + sg * 8;
  const bf16* bStage = Bt + (long)(col0 + srow) * DALL + sg * 8;
  const int wOff = wid << 10;

  const int NT = DALL >> 6;  // 56

  const int sx = lr & 7;
  const int arowb = wm * 64 + lr;
  const int browb = wn * 112 + lr;

  f32x4 acc[4][7];
  const f32x4 zero = {0.f, 0.f, 0.f, 0.f};
#pragma unroll
  for (int m = 0; m < 4; ++m)
#pragma unroll
    for (int n = 0; n < 7; ++n) acc[m][n] = zero;

#pragma unroll
  for (int i = 0; i < 4; ++i)
    async_copy16(sB + i * 8192 + wOff, bStage + (long)i * 64 * DALL);
#pragma unroll
  for (int i = 0; i < 4; ++i)
    async_copy16(sA + i * 8192 + wOff, aStage + (long)i * 64 * DALL);
#pragma unroll
  for (int i = 0; i < 4; ++i)
    async_copy16(sB + 32768 + i * 8192 + wOff, bStage + (long)i * 64 * DALL + 64);
  VMCNT4();
  BARRIER();

  bf16x8 af[4][2], bf[7][2];

  for (int t = 0; t < NT; ++t) {
    const int cur = t & 1;
    char* cA = sA + cur * 32768;
    char* cB = sB + cur * 32768;
    char* nA = sA + (cur ^ 1) * 32768;

    if (t + 1 < NT) {
      const bf16* g = aStage + (long)(t + 1) * 64;
#pragma unroll
      for (int i = 0; i < 4; ++i)
        async_copy16(nA + i * 8192 + wOff, g + (long)i * 64 * DALL);
    }
#pragma unroll
    for (int m = 0; m < 4; ++m)
#pragma unroll
      for (int kk = 0; kk < 2; ++kk)
        af[m][kk] = *(const bf16x8*)(cA + (arowb + m * 16) * 128 +
                                     ((((kk << 2) | lk) ^ sx) << 4));
#pragma unroll
    for (int n = 0; n < 7; ++n)
#pragma unroll
      for (int kk = 0; kk < 2; ++kk)
        bf[n][kk] = *(const bf16x8*)(cB + (browb + n * 16) * 128 +
                                     ((((kk << 2) | lk) ^ sx) << 4));
    __builtin_amdgcn_s_setprio(1);
#pragma unroll
    for (int m = 0; m < 4; ++m)
#pragma unroll
      for (int n = 0; n < 4; ++n)
#pragma unroll
        for (int kk = 0; kk < 2; ++kk)
          acc[m][n] = __builtin_amdgcn_mfma_f32_16x16x32_bf16(
              af[m][kk], bf[n][kk], acc[m][n], 0, 0, 0);
    __builtin_amdgcn_s_setprio(0);
    LGKM0();
    BARRIER();

    const int more = (t + 2 < NT);
    if (more) {
      const bf16* g = bStage + (long)(t + 2) * 64;
#pragma unroll
      for (int i = 0; i < 4; ++i)
        async_copy16(cB + i * 8192 + wOff, g + (long)i * 64 * DALL);
    }
    __builtin_amdgcn_s_setprio(1);
#pragma unroll
    for (int m = 0; m < 4; ++m)
#pragma unroll
      for (int n = 4; n < 7; ++n)
#pragma unroll
        for (int kk = 0; kk < 2; ++kk)
          acc[m][n] = __builtin_amdgcn_mfma_f32_16x16x32_bf16(
              af[m][kk], bf[n][kk], acc[m][n], 0, 0, 0);
    __builtin_amdgcn_s_setprio(0);
    if (more) { VMCNT4(); } else { VMCNT0(); }
    BARRIER();
  }

#pragma unroll
  for (int m = 0; m < 4; ++m) {
#pragma unroll
    for (int n = 0; n < 7; ++n) {
      const int gc = col0 + wn * 112 + n * 16 + lr;
      const float bia = bias[gc];
#pragma unroll
      for (int j = 0; j < 4; ++j) {
        const int gr = row0 + wm * 64 + m * 16 + lk * 4 + j;
        Cout[(long)gr * DALL + gc] = __float2bfloat16(acc[m][n][j] + bia);
      }
    }
  }
}

// ---------------- merged converters: vals + pw transpose + w2 transpose ----
// flat grid 13664 blocks, uniform per-block branch; each branch's inner code
// is byte-identical to the r9-verified kernels.
__global__ __launch_bounds__(256)
void all_conv(const float* __restrict__ pv, const float* __restrict__ mv,
              bf16* __restrict__ pvb, bf16* __restrict__ mvb,
              const float* __restrict__ pw, bf16* __restrict__ pwTb,
              const float* __restrict__ w2, bf16* __restrict__ w2t) {
  __shared__ float tile[32][33];
  const int idx = blockIdx.x, tid = threadIdx.x;
  if (idx < 224) {
    // vals fp32->bf16 (r9 conv2 inner code)
    const int sel = idx >= 112;
    const float* in = sel ? mv : pv;
    bf16* out = sel ? mvb : pvb;
    const int bx = sel ? idx - 112 : idx;
    const int i = (bx * 256 + tid) * 8;
    float4 a = *(const float4*)(in + i);
    float4 b = *(const float4*)(in + i + 4);
    union { bf16 h[8]; bf16x8 v; } u;
    u.h[0] = __float2bfloat16(a.x); u.h[1] = __float2bfloat16(a.y);
    u.h[2] = __float2bfloat16(a.z); u.h[3] = __float2bfloat16(a.w);
    u.h[4] = __float2bfloat16(b.x); u.h[5] = __float2bfloat16(b.y);
    u.h[6] = __float2bfloat16(b.z); u.h[7] = __float2bfloat16(b.w);
    *(bf16x8*)(out + i) = u.v;
    return;
  }
  const float* in;
  bf16* out;
  int R, C, c0, r0;
  long base;
  if (idx < 1120) {
    // pw transpose [28][256][128] -> [28][128][256] (r9 tconv params)
    const int t = idx - 224;
    c0 = (t & 3) * 32;           // over PDIM/32 = 4
    r0 = ((t >> 2) & 7) * 32;    // over MDIM/32 = 8
    base = (long)(t >> 5) * (MDIM * PDIM);
    in = pw; out = pwTb; R = MDIM; C = PDIM;
  } else {
    // w2 transpose [3584][3584] (r9 tconv params)
    const int t = idx - 1120;
    c0 = (t % 112) * 32;
    r0 = (t / 112) * 32;
    base = 0;
    in = w2; out = w2t; R = DALL; C = DALL;
  }
  const int tx = tid & 31, ty = tid >> 5;
#pragma unroll
  for (int i = 0; i < 4; ++i)
    tile[ty + i * 8][tx] = in[base + (long)(r0 + ty + i * 8) * C + c0 + tx];
  __syncthreads();
  const int cl = tid >> 3, rq = (tid & 7) * 4;
  union { bf16 h[4]; short4v v; } u;
#pragma unroll
  for (int j = 0; j < 4; ++j) u.h[j] = __float2bfloat16(tile[rq + j][cl]);
  *(short4v*)(out + base + (long)(c0 + cl) * R + r0 + rq) = u.v;
}

// ---------------- prep: single-pass convert + fused pair-mean (r9) ---------
__global__ __launch_bounds__(256)
void prep_kernel(const float* __restrict__ ps, const float* __restrict__ mac,
                 const float* __restrict__ pkeys, const float* __restrict__ mkeys,
                 bf16* __restrict__ psb, bf16* __restrict__ att) {
  const int b = blockIdx.x, tid = threadIdx.x;
  __shared__ float q[PDIM];
  __shared__ float mrow[MDIM];
  __shared__ float red[16][PDIM];
  const float* prow = ps + (long)b * DALL;
  if (tid < MDIM) mrow[tid] = mac[(long)b * MDIM + tid];
  float a8[8];
#pragma unroll
  for (int j = 0; j < 8; ++j) a8[j] = 0.f;
  for (int i = tid * 8; i < DALL; i += 2048) {
    float4 a = *(const float4*)(prow + i);
    float4 c = *(const float4*)(prow + i + 4);
    union { bf16 h[8]; bf16x8 v; } u;
    u.h[0] = __float2bfloat16(a.x); u.h[1] = __float2bfloat16(a.y);
    u.h[2] = __float2bfloat16(a.z); u.h[3] = __float2bfloat16(a.w);
    u.h[4] = __float2bfloat16(c.x); u.h[5] = __float2bfloat16(c.y);
    u.h[6] = __float2bfloat16(c.z); u.h[7] = __float2bfloat16(c.w);
    *(bf16x8*)(psb + (long)b * DALL + i) = u.v;
    a8[0] += a.x; a8[1] += a.y; a8[2] += a.z; a8[3] += a.w;
    a8[4] += c.x; a8[5] += c.y; a8[6] += c.z; a8[7] += c.w;
  }
  {
    float* rp = &red[tid >> 4][(tid & 15) * 8];
    *(f32x4*)rp = *(f32x4*)&a8[0];
    *(f32x4*)(rp + 4) = *(f32x4*)&a8[4];
  }
  __syncthreads();
  if (tid < PDIM) {
    float s = 0.f;
#pragma unroll
    for (int k = 0; k < 16; ++k) s += red[k][tid];
    q[tid] = s * (1.f / NPAIR);
  }
  __syncthreads();
  const int wid = tid >> 6, lane = tid & 63;
  if (wid == 0) {
    float sc = 0.f;
    const float* kr = pkeys + lane * PDIM;
    for (int d = 0; d < PDIM; ++d) sc += q[d] * kr[d];
    sc *= 0.08838834764831845f;
    float mx = sc;
#pragma unroll
    for (int m = 32; m; m >>= 1) mx = fmaxf(mx, __shfl_xor(mx, m));
    float e = expf(sc - mx);
    float ssum = e;
#pragma unroll
    for (int m = 32; m; m >>= 1) ssum += __shfl_xor(ssum, m);
    att[(long)b * 128 + lane] = __float2bfloat16(e / ssum);
  } else if (wid == 1) {
    float sc = 0.f;
    const float* kr = mkeys + lane * MDIM;
    for (int d = 0; d < MDIM; ++d) sc += mrow[d] * kr[d];
    sc *= 0.0625f;
    float mx = sc;
#pragma unroll
    for (int m = 32; m; m >>= 1) mx = fmaxf(mx, __shfl_xor(mx, m));
    float e = expf(sc - mx);
    float ssum = e;
#pragma unroll
    for (int m = 32; m; m >>= 1) ssum += __shfl_xor(ssum, m);
    att[(long)b * 128 + 64 + lane] = __float2bfloat16(e / ssum);
  }
}

// ---------------- CVt precompute DIRECT from fp32 w1 (r7/r9, verified) -----
__global__ __launch_bounds__(256)
void precompute_direct(const float* __restrict__ w1, const bf16* __restrict__ pvb,
                       const bf16* __restrict__ mvb, float* __restrict__ part) {
  __shared__ __align__(16) bf16 sAt[256 * 40];
  __shared__ __align__(16) bf16 sBt[64 * 32];
  const int tid = threadIdx.x, wid = tid >> 6, lane = tid & 63;
  const int lr = lane & 15, lk = lane >> 4;
  const int n0 = blockIdx.x * 256;
  const int ksb = blockIdx.y;
  const int kbase = ksb * KCH2;
  const bf16* vb = (ksb < 8) ? pvb : mvb;
  const int kcol0 = (ksb < 8) ? kbase : kbase - DALL;

  const int bs = tid >> 2;
  const int bgs = (tid & 3) ^ (bs & 3);

  f32x4 acc[4][4];
  const f32x4 zero = {0.f, 0.f, 0.f, 0.f};
#pragma unroll
  for (int m = 0; m < 4; ++m)
#pragma unroll
    for (int n = 0; n < 4; ++n) acc[m][n] = zero;

  for (int kt = 0; kt < KCH2; kt += 32) {
    __syncthreads();
    {
      const float* src = w1 + (long)(kbase + kt) * DALL + n0 + tid;
      bf16* dst = sAt + tid * 40;
#pragma unroll
      for (int r8 = 0; r8 < 32; r8 += 4) {
        union { bf16 h[4]; short4v v; } u;
#pragma unroll
        for (int j = 0; j < 4; ++j)
          u.h[j] = __float2bfloat16(src[(long)(r8 + j) * DALL]);
        *(short4v*)(dst + r8) = u.v;
      }
    }
    async_copy16((char*)sBt + tid * 16,
                 vb + (long)bs * DALL + kcol0 + kt + bgs * 8);
    __syncthreads();
    bf16x8 af[4], bfr[4];
#pragma unroll
    for (int m = 0; m < 4; ++m)
      af[m] = *(const bf16x8*)((const char*)sAt +
                               ((wid * 64 + m * 16 + lr) * 40 + lk * 8) * 2);
#pragma unroll
    for (int n = 0; n < 4; ++n) {
      const int s = n * 16 + lr;
      bfr[n] = *(const bf16x8*)((const char*)sBt + s * 64 + ((lk ^ (s & 3)) << 4));
    }
#pragma unroll
    for (int m = 0; m < 4; ++m)
#pragma unroll
      for (int n = 0; n < 4; ++n)
        acc[m][n] =
            __builtin_amdgcn_mfma_f32_16x16x32_bf16(af[m], bfr[n], acc[m][n], 0, 0, 0);
  }
#pragma unroll
  for (int m = 0; m < 4; ++m)
#pragma unroll
    for (int n = 0; n < 4; ++n)
#pragma unroll
      for (int j = 0; j < 4; ++j) {
        const int gn = n0 + wid * 64 + m * 16 + lk * 4 + j;
        const int s = n * 16 + lr;
        part[((long)ksb * DALL + gn) * 64 + s] = acc[m][n][j];
      }
}

// ---------------- reduce K-split partials -> CVt bf16 [3584][128] ----------
__global__ __launch_bounds__(256)
void reduce_cvt(const float* __restrict__ part, bf16* __restrict__ cvt) {
  const long i4 = ((long)blockIdx.x * 256 + threadIdx.x) * 4;
  const int n = (int)(i4 >> 7), sc = (int)(i4 & 127);
  const int half = sc >> 6, s0 = sc & 63;
  f32x4 s = {0.f, 0.f, 0.f, 0.f};
#pragma unroll
  for (int j = 0; j < 8; ++j)
    s += *(const f32x4*)(part + ((long)(half * 8 + j) * DALL + n) * 64 + s0);
#pragma unroll
  for (int k = 0; k < 4; ++k) cvt[i4 + k] = __float2bfloat16(s[k]);
}

// ---------------- thin GEMM K=128 (BK=64, swizzled, r7/r9) -----------------
__global__ __launch_bounds__(256)
void gemm_thin(const bf16* __restrict__ att, const bf16* __restrict__ cvt,
               bf16* __restrict__ hpre, const float* __restrict__ bias) {
  __shared__ __align__(16) bf16 sA[128 * 64];
  __shared__ __align__(16) bf16 sB[128 * 64];
  const int tid = threadIdx.x, wid = tid >> 6, lane = tid & 63;
  const int lr = lane & 15, lk = lane >> 4;
  const int col0 = blockIdx.x * 128, row0 = blockIdx.y * 128;
  const int srl = lane >> 3;
  const int sgl = (lane & 7) ^ srl;
  const int sx = lr & 7;

  f32x4 acc[2][8];
  const f32x4 zero = {0.f, 0.f, 0.f, 0.f};
#pragma unroll
  for (int m = 0; m < 2; ++m)
#pragma unroll
    for (int n = 0; n < 8; ++n) acc[m][n] = zero;

  for (int kt = 0; kt < 2; ++kt) {
    __syncthreads();
#pragma unroll
    for (int i = 0; i < 4; ++i) {
      const int r = i * 32 + wid * 8 + srl;
      async_copy16((char*)sA + i * 4096 + wid * 1024,
                   att + (long)(row0 + r) * 128 + kt * 64 + sgl * 8);
      async_copy16((char*)sB + i * 4096 + wid * 1024,
                   cvt + (long)(col0 + r) * 128 + kt * 64 + sgl * 8);
    }
    __syncthreads();
#pragma unroll
    for (int kk = 0; kk < 2; ++kk) {
      bf16x8 a0[2], b0[8];
      const int gb = (((kk << 2) | lk) ^ sx) << 4;
#pragma unroll
      for (int m = 0; m < 2; ++m)
        a0[m] = *(const bf16x8*)((const char*)sA + (wid * 32 + m * 16 + lr) * 128 + gb);
#pragma unroll
      for (int n = 0; n < 8; ++n)
        b0[n] = *(const bf16x8*)((const char*)sB + (n * 16 + lr) * 128 + gb);
#pragma unroll
      for (int m = 0; m < 2; ++m)
#pragma unroll
        for (int n = 0; n < 8; ++n)
          acc[m][n] = __builtin_amdgcn_mfma_f32_16x16x32_bf16(
              a0[m], b0[n], acc[m][n], 0, 0, 0);
    }
  }
#pragma unroll
  for (int m = 0; m < 2; ++m) {
#pragma unroll
    for (int n = 0; n < 8; ++n) {
      const int gc = col0 + n * 16 + lr;
      const float bia = bias[gc];
#pragma unroll
      for (int j = 0; j < 4; ++j) {
        const int gr = row0 + wid * 32 + m * 16 + lk * 4 + j;
        hpre[(long)gr * DALL + gc] = __float2bfloat16(acc[m][n][j] + bia);
      }
    }
  }
}

// ---------------- LayerNorm + exact GELU, bf16 in -> bf16 out (r7/r9) ------
__global__ __launch_bounds__(256)
void ln_gelu_kernel(const bf16* __restrict__ h, const float* __restrict__ g,
                    const float* __restrict__ bb, bf16* __restrict__ h2) {
  const int row = blockIdx.x, tid = threadIdx.x;
  const bf16* x = h + (long)row * DALL;
  float v[14];
  float s1 = 0.f, s2 = 0.f;
#pragma unroll
  for (int i = 0; i < 14; ++i) {
    v[i] = __bfloat162float(x[i * 256 + tid]);
    s1 += v[i];
    s2 += v[i] * v[i];
  }
#pragma unroll
  for (int m = 32; m; m >>= 1) {
    s1 += __shfl_xor(s1, m);
    s2 += __shfl_xor(s2, m);
  }
  __shared__ float r1[4], r2[4];
  const int wid = tid >> 6, lane = tid & 63;
  if (lane == 0) {
    r1[wid] = s1;
    r2[wid] = s2;
  }
  __syncthreads();
  s1 = r1[0] + r1[1] + r1[2] + r1[3];
  s2 = r2[0] + r2[1] + r2[2] + r2[3];
  const float mean = s1 * (1.f / DALL);
  const float var = s2 * (1.f / DALL) - mean * mean;
  const float rstd = rsqrtf(var + 1e-5f);
#pragma unroll
  for (int i = 0; i < 14; ++i) {
    const int c = i * 256 + tid;
    const float y = (v[i] - mean) * rstd * g[c] + bb[c];
    const float ge = 0.5f * y * (1.f + erff(y * 0.7071067811865475f));
    h2[(long)row * DALL + c] = __float2bfloat16(ge);
  }
}

// ---------------- per-pair GEMM (K=256, BK=64 swizzled) + LN (r7/r9) -------
__global__ __launch_bounds__(256)
void pair_final(const bf16* __restrict__ psb, const bf16* __restrict__ fusedb,
                const bf16* __restrict__ pwT, const float* __restrict__ pb,
                const float* __restrict__ lng, const float* __restrict__ lnb,
                float* __restrict__ out) {
  __shared__ __align__(16) bf16 sA[128 * 64];
  __shared__ __align__(16) bf16 sB[128 * 64];
  const int tid = threadIdx.x, wid = tid >> 6, lane = tid & 63;
  const int lr = lane & 15, lk = lane >> 4;
  const int p = blockIdx.y, row0 = blockIdx.x * 128;
  const int srl = lane >> 3;
  const int sgl = (lane & 7) ^ srl;
  const int sx = lr & 7;
  const bf16* pwp = pwT + (long)p * (PDIM * MDIM);

  f32x4 acc[2][8];
  const f32x4 zero = {0.f, 0.f, 0.f, 0.f};
#pragma unroll
  for (int m = 0; m < 2; ++m)
#pragma unroll
    for (int n = 0; n < 8; ++n) acc[m][n] = zero;

  for (int kt = 0; kt < 4; ++kt) {
    __syncthreads();
    const bf16* Asrc = (kt < 2) ? psb : fusedb;
    const int acol = p * PDIM + (kt & 1) * 64;
#pragma unroll
    for (int i = 0; i < 4; ++i) {
      const int r = i * 32 + wid * 8 + srl;
      async_copy16((char*)sA + i * 4096 + wid * 1024,
                   Asrc + (long)(row0 + r) * DALL + acol + sgl * 8);
      async_copy16((char*)sB + i * 4096 + wid * 1024,
                   pwp + (long)r * MDIM + kt * 64 + sgl * 8);
    }
    __syncthreads();
#pragma unroll
    for (int kk = 0; kk < 2; ++kk) {
      bf16x8 a0[2], b0[8];
      const int gb = (((kk << 2) | lk) ^ sx) << 4;
#pragma unroll
      for (int m = 0; m < 2; ++m)
        a0[m] = *(const bf16x8*)((const char*)sA + (wid * 32 + m * 16 + lr) * 128 + gb);
#pragma unroll
      for (int n = 0; n < 8; ++n)
        b0[n] = *(const bf16x8*)((const char*)sB + (n * 16 + lr) * 128 + gb);
#pragma unroll
      for (int m = 0; m < 2; ++m)
#pragma unroll
        for (int n = 0; n < 8; ++n)
          acc[m][n] = __builtin_amdgcn_mfma_f32_16x16x32_bf16(
              a0[m], b0[n], acc[m][n], 0, 0, 0);
    }
  }
  float g_[8], b_[8], pb_[8];
#pragma unroll
  for (int n = 0; n < 8; ++n) {
    const int c = n * 16 + lr;
    g_[n] = lng[p * PDIM + c];
    b_[n] = lnb[p * PDIM + c];
    pb_[n] = pb[p * PDIM + c];
  }
#pragma unroll
  for (int m = 0; m < 2; ++m) {
#pragma unroll
    for (int j = 0; j < 4; ++j) {
      float vv[8];
      float s1 = 0.f, s2 = 0.f;
#pragma unroll
      for (int n = 0; n < 8; ++n) {
        vv[n] = acc[m][n][j] + pb_[n];
        s1 += vv[n];
        s2 += vv[n] * vv[n];
      }
#pragma unroll
      for (int msk = 1; msk <= 8; msk <<= 1) {
        s1 += __shfl_xor(s1, msk);
        s2 += __shfl_xor(s2, msk);
      }
      const float mean = s1 * (1.f / 128.f);
      const float var = s2 * (1.f / 128.f) - mean * mean;
      const float rstd = rsqrtf(var + 1e-5f);
      const int gr = row0 + wid * 32 + m * 16 + lk * 4 + j;
      float* orow = out + ((long)gr * NPAIR + p) * PDIM;
#pragma unroll
      for (int n = 0; n < 8; ++n)
        orow[n * 16 + lr] = (vv[n] - mean) * rstd * g_[n] + b_[n];
    }
  }
}

// ---------------------------------------------------------------------------
extern "C" void kernel_launch(void* const* d_in, const int* in_sizes, int n_in,
                              void* d_out, int out_size, void* d_ws, size_t ws_size,
                              hipStream_t stream) {
  (void)in_sizes; (void)n_in; (void)out_size; (void)ws_size;
  const float* ps   = (const float*)d_in[0];
  const float* mac  = (const float*)d_in[1];
  const float* pkey = (const float*)d_in[2];
  const float* pval = (const float*)d_in[3];
  const float* mkey = (const float*)d_in[4];
  const float* mval = (const float*)d_in[5];
  const float* w1   = (const float*)d_in[6];
  const float* b1   = (const float*)d_in[7];
  const float* lng1 = (const float*)d_in[8];
  const float* lnb1 = (const float*)d_in[9];
  const float* w2   = (const float*)d_in[10];
  const float* b2   = (const float*)d_in[11];
  const float* pw   = (const float*)d_in[12];
  const float* pb   = (const float*)d_in[13];
  const float* plng = (const float*)d_in[14];
  const float* plnb = (const float*)d_in[15];
  float* out = (float*)d_out;

  char* w = (char*)d_ws;
  size_t off = 0;
  auto carve = [&](size_t bytes) {
    char* pp = w + off;
    off += (bytes + 255) & ~(size_t)255;
    return pp;
  };
  bf16* psb   = (bf16*)carve((size_t)B_SZ * DALL * 2);
  bf16* w2t   = (bf16*)carve((size_t)(DALL + 32) * DALL * 2);  // +32 pad rows
  bf16* pvb   = (bf16*)carve((size_t)NSLOT * DALL * 2);
  bf16* mvb   = (bf16*)carve((size_t)NSLOT * DALL * 2);
  bf16* pwTb  = (bf16*)carve((size_t)NPAIR * PDIM * MDIM * 2);
  bf16* att   = (bf16*)carve((size_t)B_SZ * 128 * 2);
  bf16* cvt   = (bf16*)carve((size_t)DALL * 128 * 2);
  float* part = (float*)carve((size_t)KS2 * DALL * 64 * 4);
  bf16* hpreb = (bf16*)carve((size_t)B_SZ * DALL * 2);
  bf16* h2    = (bf16*)carve((size_t)B_SZ * DALL * 2);
  bf16* fusedb = hpreb;  // alias: hpreb last read by ln_gelu

  // merged converters: vals (224) + pw transpose (896) + w2 transpose (12544)
  all_conv<<<dim3(13664), 256, 0, stream>>>(pval, mval, pvb, mvb, pw, pwTb, w2, w2t);
  prep_kernel<<<dim3(B_SZ), 256, 0, stream>>>(ps, mac, pkey, mkey, psb, att);
  precompute_direct<<<dim3(DALL / 256, KS2), 256, 0, stream>>>(w1, pvb, mvb, part);
  reduce_cvt<<<dim3(DALL * 128 / 1024), 256, 0, stream>>>(part, cvt);
  gemm_thin<<<dim3(DALL / 128, B_SZ / 128), 256, 0, stream>>>(att, cvt, hpreb, b1);
  ln_gelu_kernel<<<dim3(B_SZ), 256, 0, stream>>>(hpreb, lng1, lnb1, h2);
  gemm224<<<dim3(256), 512, 0, stream>>>(h2, w2t, fusedb, b2);
  pair_final<<<dim3(B_SZ / 128, NPAIR), 256, 0, stream>>>(
      psb, fusedb, pwTb, pb, plng, plnb, out);
}

// Round 12
// 267.922 us; speedup vs baseline: 1.1307x; 1.0265x over previous
//
#include <hip/hip_runtime.h>
#include <hip/hip_bf16.h>
#include <math.h>

// CrossPairMemory round 12: r11 (275.0us verified) + two mechanical changes:
// (1) KSPLIT 16->32 for precompute_direct (448 blocks -> cross-block TLP
//     hides w1 HBM latency); reduce_cvt sums 16 partials.
// (2) prep merged into the all_conv flat grid (inner code identical) -> one
//     fewer launch. No inner-loop/schedule changes anywhere else.

#define B_SZ  4096
#define NPAIR 28
#define PDIM  128
#define MDIM  256
#define NSLOT 64
#define DALL  3584
#define DCAT  7168
#define KS2   32
#define KCH2  224   // DCAT / KS2

typedef __hip_bfloat16 bf16;
typedef __attribute__((ext_vector_type(8))) short bf16x8;
typedef __attribute__((ext_vector_type(4))) short short4v;
typedef __attribute__((ext_vector_type(4))) float f32x4;

#define BARRIER() asm volatile("s_barrier" ::: "memory")
#define LGKM0()   asm volatile("s_waitcnt lgkmcnt(0)" ::: "memory")
#define VMCNT4()  asm volatile("s_waitcnt vmcnt(4)" ::: "memory")
#define VMCNT0()  asm volatile("s_waitcnt vmcnt(0)" ::: "memory")

__device__ __forceinline__ void async_copy16(void* lds, const void* g) {
  __builtin_amdgcn_global_load_lds((__attribute__((address_space(1))) void*)g,
                                   (__attribute__((address_space(3))) void*)lds,
                                   16, 0, 0);
}

// ============== 256x224x64 2-phase GEMM (r6/r9/r11 schedule, 95us) =========
__global__ __launch_bounds__(512, 2)
void gemm224(const bf16* __restrict__ A, const bf16* __restrict__ Bt,
             bf16* __restrict__ Cout, const float* __restrict__ bias) {
  __shared__ __align__(16) char smem[131072];
  const int tid = threadIdx.x;
  const int wid = tid >> 6, lane = tid & 63;
  const int lr = lane & 15, lk = lane >> 4;
  const int wm = wid >> 1, wn = wid & 1;
  const int swz = ((int)blockIdx.x & 7) * 32 + ((int)blockIdx.x >> 3);
  const int bx = swz & 15, by = swz >> 4;
  const int col0 = bx * 224, row0 = by * 256;

  char* sA = smem;
  char* sB = smem + 65536;

  const int srow = tid >> 3;
  const int sg = (tid & 7) ^ (srow & 7);
  const bf16* aStage = A + (long)(row0 + srow) * DALL + sg * 8;
  const bf16* bStage = Bt + (long)(col0 + srow) * DALL + sg * 8;
  const int wOff = wid << 10;

  const int NT = DALL >> 6;  // 56

  const int sx = lr & 7;
  const int arowb = wm * 64 + lr;
  const int browb = wn * 112 + lr;

  f32x4 acc[4][7];
  const f32x4 zero = {0.f, 0.f, 0.f, 0.f};
#pragma unroll
  for (int m = 0; m < 4; ++m)
#pragma unroll
    for (int n = 0; n < 7; ++n) acc[m][n] = zero;

#pragma unroll
  for (int i = 0; i < 4; ++i)
    async_copy16(sB + i * 8192 + wOff, bStage + (long)i * 64 * DALL);
#pragma unroll
  for (int i = 0; i < 4; ++i)
    async_copy16(sA + i * 8192 + wOff, aStage + (long)i * 64 * DALL);
#pragma unroll
  for (int i = 0; i < 4; ++i)
    async_copy16(sB + 32768 + i * 8192 + wOff, bStage + (long)i * 64 * DALL + 64);
  VMCNT4();
  BARRIER();

  bf16x8 af[4][2], bf[7][2];

  for (int t = 0; t < NT; ++t) {
    const int cur = t & 1;
    char* cA = sA + cur * 32768;
    char* cB = sB + cur * 32768;
    char* nA = sA + (cur ^ 1) * 32768;

    if (t + 1 < NT) {
      const bf16* g = aStage + (long)(t + 1) * 64;
#pragma unroll
      for (int i = 0; i < 4; ++i)
        async_copy16(nA + i * 8192 + wOff, g + (long)i * 64 * DALL);
    }
#pragma unroll
    for (int m = 0; m < 4; ++m)
#pragma unroll
      for (int kk = 0; kk < 2; ++kk)
        af[m][kk] = *(const bf16x8*)(cA + (arowb + m * 16) * 128 +
                                     ((((kk << 2) | lk) ^ sx) << 4));
#pragma unroll
    for (int n = 0; n < 7; ++n)
#pragma unroll
      for (int kk = 0; kk < 2; ++kk)
        bf[n][kk] = *(const bf16x8*)(cB + (browb + n * 16) * 128 +
                                     ((((kk << 2) | lk) ^ sx) << 4));
    __builtin_amdgcn_s_setprio(1);
#pragma unroll
    for (int m = 0; m < 4; ++m)
#pragma unroll
      for (int n = 0; n < 4; ++n)
#pragma unroll
        for (int kk = 0; kk < 2; ++kk)
          acc[m][n] = __builtin_amdgcn_mfma_f32_16x16x32_bf16(
              af[m][kk], bf[n][kk], acc[m][n], 0, 0, 0);
    __builtin_amdgcn_s_setprio(0);
    LGKM0();
    BARRIER();

    const int more = (t + 2 < NT);
    if (more) {
      const bf16* g = bStage + (long)(t + 2) * 64;
#pragma unroll
      for (int i = 0; i < 4; ++i)
        async_copy16(cB + i * 8192 + wOff, g + (long)i * 64 * DALL);
    }
    __builtin_amdgcn_s_setprio(1);
#pragma unroll
    for (int m = 0; m < 4; ++m)
#pragma unroll
      for (int n = 4; n < 7; ++n)
#pragma unroll
        for (int kk = 0; kk < 2; ++kk)
          acc[m][n] = __builtin_amdgcn_mfma_f32_16x16x32_bf16(
              af[m][kk], bf[n][kk], acc[m][n], 0, 0, 0);
    __builtin_amdgcn_s_setprio(0);
    if (more) { VMCNT4(); } else { VMCNT0(); }
    BARRIER();
  }

#pragma unroll
  for (int m = 0; m < 4; ++m) {
#pragma unroll
    for (int n = 0; n < 7; ++n) {
      const int gc = col0 + wn * 112 + n * 16 + lr;
      const float bia = bias[gc];
#pragma unroll
      for (int j = 0; j < 4; ++j) {
        const int gr = row0 + wm * 64 + m * 16 + lk * 4 + j;
        Cout[(long)gr * DALL + gc] = __float2bfloat16(acc[m][n][j] + bia);
      }
    }
  }
}

// ---------------- merged: vals + pw/w2 transpose + prep --------------------
// flat grid 17760; per-block uniform branch; each branch's inner code is
// byte-identical to the r11-verified kernels.
__global__ __launch_bounds__(256)
void all_conv(const float* __restrict__ pv, const float* __restrict__ mv,
              bf16* __restrict__ pvb, bf16* __restrict__ mvb,
              const float* __restrict__ pw, bf16* __restrict__ pwTb,
              const float* __restrict__ w2, bf16* __restrict__ w2t,
              const float* __restrict__ ps, const float* __restrict__ mac,
              const float* __restrict__ pkeys, const float* __restrict__ mkeys,
              bf16* __restrict__ psb, bf16* __restrict__ att) {
  __shared__ float tile[32][33];
  __shared__ float q[PDIM];
  __shared__ float mrow[MDIM];
  __shared__ float red[16][PDIM];
  const int idx = blockIdx.x, tid = threadIdx.x;
  if (idx >= 13664) {
    // ---- prep branch (r9/r11 inner code) ----
    const int b = idx - 13664;
    const float* prow = ps + (long)b * DALL;
    if (tid < MDIM) mrow[tid] = mac[(long)b * MDIM + tid];
    float a8[8];
#pragma unroll
    for (int j = 0; j < 8; ++j) a8[j] = 0.f;
    for (int i = tid * 8; i < DALL; i += 2048) {
      float4 a = *(const float4*)(prow + i);
      float4 c = *(const float4*)(prow + i + 4);
      union { bf16 h[8]; bf16x8 v; } u;
      u.h[0] = __float2bfloat16(a.x); u.h[1] = __float2bfloat16(a.y);
      u.h[2] = __float2bfloat16(a.z); u.h[3] = __float2bfloat16(a.w);
      u.h[4] = __float2bfloat16(c.x); u.h[5] = __float2bfloat16(c.y);
      u.h[6] = __float2bfloat16(c.z); u.h[7] = __float2bfloat16(c.w);
      *(bf16x8*)(psb + (long)b * DALL + i) = u.v;
      a8[0] += a.x; a8[1] += a.y; a8[2] += a.z; a8[3] += a.w;
      a8[4] += c.x; a8[5] += c.y; a8[6] += c.z; a8[7] += c.w;
    }
    {
      float* rp = &red[tid >> 4][(tid & 15) * 8];
      *(f32x4*)rp = *(f32x4*)&a8[0];
      *(f32x4*)(rp + 4) = *(f32x4*)&a8[4];
    }
    __syncthreads();
    if (tid < PDIM) {
      float s = 0.f;
#pragma unroll
      for (int k = 0; k < 16; ++k) s += red[k][tid];
      q[tid] = s * (1.f / NPAIR);
    }
    __syncthreads();
    const int wid = tid >> 6, lane = tid & 63;
    if (wid == 0) {
      float sc = 0.f;
      const float* kr = pkeys + lane * PDIM;
      for (int d = 0; d < PDIM; ++d) sc += q[d] * kr[d];
      sc *= 0.08838834764831845f;
      float mx = sc;
#pragma unroll
      for (int m = 32; m; m >>= 1) mx = fmaxf(mx, __shfl_xor(mx, m));
      float e = expf(sc - mx);
      float ssum = e;
#pragma unroll
      for (int m = 32; m; m >>= 1) ssum += __shfl_xor(ssum, m);
      att[(long)b * 128 + lane] = __float2bfloat16(e / ssum);
    } else if (wid == 1) {
      float sc = 0.f;
      const float* kr = mkeys + lane * MDIM;
      for (int d = 0; d < MDIM; ++d) sc += mrow[d] * kr[d];
      sc *= 0.0625f;
      float mx = sc;
#pragma unroll
      for (int m = 32; m; m >>= 1) mx = fmaxf(mx, __shfl_xor(mx, m));
      float e = expf(sc - mx);
      float ssum = e;
#pragma unroll
      for (int m = 32; m; m >>= 1) ssum += __shfl_xor(ssum, m);
      att[(long)b * 128 + 64 + lane] = __float2bfloat16(e / ssum);
    }
    return;
  }
  if (idx < 224) {
    // ---- vals fp32->bf16 (r11 inner code) ----
    const int sel = idx >= 112;
    const float* in = sel ? mv : pv;
    bf16* out = sel ? mvb : pvb;
    const int bx = sel ? idx - 112 : idx;
    const int i = (bx * 256 + tid) * 8;
    float4 a = *(const float4*)(in + i);
    float4 b = *(const float4*)(in + i + 4);
    union { bf16 h[8]; bf16x8 v; } u;
    u.h[0] = __float2bfloat16(a.x); u.h[1] = __float2bfloat16(a.y);
    u.h[2] = __float2bfloat16(a.z); u.h[3] = __float2bfloat16(a.w);
    u.h[4] = __float2bfloat16(b.x); u.h[5] = __float2bfloat16(b.y);
    u.h[6] = __float2bfloat16(b.z); u.h[7] = __float2bfloat16(b.w);
    *(bf16x8*)(out + i) = u.v;
    return;
  }
  // ---- transpose branches (r11 inner code) ----
  const float* in;
  bf16* out;
  int R, C, c0, r0;
  long base;
  if (idx < 1120) {
    const int t = idx - 224;
    c0 = (t & 3) * 32;
    r0 = ((t >> 2) & 7) * 32;
    base = (long)(t >> 5) * (MDIM * PDIM);
    in = pw; out = pwTb; R = MDIM; C = PDIM;
  } else {
    const int t = idx - 1120;
    c0 = (t % 112) * 32;
    r0 = (t / 112) * 32;
    base = 0;
    in = w2; out = w2t; R = DALL; C = DALL;
  }
  const int tx = tid & 31, ty = tid >> 5;
#pragma unroll
  for (int i = 0; i < 4; ++i)
    tile[ty + i * 8][tx] = in[base + (long)(r0 + ty + i * 8) * C + c0 + tx];
  __syncthreads();
  const int cl = tid >> 3, rq = (tid & 7) * 4;
  union { bf16 h[4]; short4v v; } u;
#pragma unroll
  for (int j = 0; j < 4; ++j) u.h[j] = __float2bfloat16(tile[rq + j][cl]);
  *(short4v*)(out + base + (long)(c0 + cl) * R + r0 + rq) = u.v;
}

// ---------------- CVt precompute DIRECT from fp32 w1 (KSPLIT=32) -----------
__global__ __launch_bounds__(256)
void precompute_direct(const float* __restrict__ w1, const bf16* __restrict__ pvb,
                       const bf16* __restrict__ mvb, float* __restrict__ part) {
  __shared__ __align__(16) bf16 sAt[256 * 40];
  __shared__ __align__(16) bf16 sBt[64 * 32];
  const int tid = threadIdx.x, wid = tid >> 6, lane = tid & 63;
  const int lr = lane & 15, lk = lane >> 4;
  const int n0 = blockIdx.x * 256;
  const int ksb = blockIdx.y;
  const int kbase = ksb * KCH2;
  const bf16* vb = (ksb < 16) ? pvb : mvb;
  const int kcol0 = (ksb < 16) ? kbase : kbase - DALL;

  const int bs = tid >> 2;
  const int bgs = (tid & 3) ^ (bs & 3);

  f32x4 acc[4][4];
  const f32x4 zero = {0.f, 0.f, 0.f, 0.f};
#pragma unroll
  for (int m = 0; m < 4; ++m)
#pragma unroll
    for (int n = 0; n < 4; ++n) acc[m][n] = zero;

  for (int kt = 0; kt < KCH2; kt += 32) {
    __syncthreads();
    {
      const float* src = w1 + (long)(kbase + kt) * DALL + n0 + tid;
      bf16* dst = sAt + tid * 40;
#pragma unroll
      for (int r8 = 0; r8 < 32; r8 += 4) {
        union { bf16 h[4]; short4v v; } u;
#pragma unroll
        for (int j = 0; j < 4; ++j)
          u.h[j] = __float2bfloat16(src[(long)(r8 + j) * DALL]);
        *(short4v*)(dst + r8) = u.v;
      }
    }
    async_copy16((char*)sBt + tid * 16,
                 vb + (long)bs * DALL + kcol0 + kt + bgs * 8);
    __syncthreads();
    bf16x8 af[4], bfr[4];
#pragma unroll
    for (int m = 0; m < 4; ++m)
      af[m] = *(const bf16x8*)((const char*)sAt +
                               ((wid * 64 + m * 16 + lr) * 40 + lk * 8) * 2);
#pragma unroll
    for (int n = 0; n < 4; ++n) {
      const int s = n * 16 + lr;
      bfr[n] = *(const bf16x8*)((const char*)sBt + s * 64 + ((lk ^ (s & 3)) << 4));
    }
#pragma unroll
    for (int m = 0; m < 4; ++m)
#pragma unroll
      for (int n = 0; n < 4; ++n)
        acc[m][n] =
            __builtin_amdgcn_mfma_f32_16x16x32_bf16(af[m], bfr[n], acc[m][n], 0, 0, 0);
  }
#pragma unroll
  for (int m = 0; m < 4; ++m)
#pragma unroll
    for (int n = 0; n < 4; ++n)
#pragma unroll
      for (int j = 0; j < 4; ++j) {
        const int gn = n0 + wid * 64 + m * 16 + lk * 4 + j;
        const int s = n * 16 + lr;
        part[((long)ksb * DALL + gn) * 64 + s] = acc[m][n][j];
      }
}

// ---------------- reduce K-split partials -> CVt bf16 [3584][128] ----------
__global__ __launch_bounds__(256)
void reduce_cvt(const float* __restrict__ part, bf16* __restrict__ cvt) {
  const long i4 = ((long)blockIdx.x * 256 + threadIdx.x) * 4;
  const int n = (int)(i4 >> 7), sc = (int)(i4 & 127);
  const int half = sc >> 6, s0 = sc & 63;
  f32x4 s = {0.f, 0.f, 0.f, 0.f};
#pragma unroll
  for (int j = 0; j < 16; ++j)
    s += *(const f32x4*)(part + ((long)(half * 16 + j) * DALL + n) * 64 + s0);
#pragma unroll
  for (int k = 0; k < 4; ++k) cvt[i4 + k] = __float2bfloat16(s[k]);
}

// ---------------- thin GEMM K=128 (BK=64, swizzled, r7/r11) ----------------
__global__ __launch_bounds__(256)
void gemm_thin(const bf16* __restrict__ att, const bf16* __restrict__ cvt,
               bf16* __restrict__ hpre, const float* __restrict__ bias) {
  __shared__ __align__(16) bf16 sA[128 * 64];
  __shared__ __align__(16) bf16 sB[128 * 64];
  const int tid = threadIdx.x, wid = tid >> 6, lane = tid & 63;
  const int lr = lane & 15, lk = lane >> 4;
  const int col0 = blockIdx.x * 128, row0 = blockIdx.y * 128;
  const int srl = lane >> 3;
  const int sgl = (lane & 7) ^ srl;
  const int sx = lr & 7;

  f32x4 acc[2][8];
  const f32x4 zero = {0.f, 0.f, 0.f, 0.f};
#pragma unroll
  for (int m = 0; m < 2; ++m)
#pragma unroll
    for (int n = 0; n < 8; ++n) acc[m][n] = zero;

  for (int kt = 0; kt < 2; ++kt) {
    __syncthreads();
#pragma unroll
    for (int i = 0; i < 4; ++i) {
      const int r = i * 32 + wid * 8 + srl;
      async_copy16((char*)sA + i * 4096 + wid * 1024,
                   att + (long)(row0 + r) * 128 + kt * 64 + sgl * 8);
      async_copy16((char*)sB + i * 4096 + wid * 1024,
                   cvt + (long)(col0 + r) * 128 + kt * 64 + sgl * 8);
    }
    __syncthreads();
#pragma unroll
    for (int kk = 0; kk < 2; ++kk) {
      bf16x8 a0[2], b0[8];
      const int gb = (((kk << 2) | lk) ^ sx) << 4;
#pragma unroll
      for (int m = 0; m < 2; ++m)
        a0[m] = *(const bf16x8*)((const char*)sA + (wid * 32 + m * 16 + lr) * 128 + gb);
#pragma unroll
      for (int n = 0; n < 8; ++n)
        b0[n] = *(const bf16x8*)((const char*)sB + (n * 16 + lr) * 128 + gb);
#pragma unroll
      for (int m = 0; m < 2; ++m)
#pragma unroll
        for (int n = 0; n < 8; ++n)
          acc[m][n] = __builtin_amdgcn_mfma_f32_16x16x32_bf16(
              a0[m], b0[n], acc[m][n], 0, 0, 0);
    }
  }
#pragma unroll
  for (int m = 0; m < 2; ++m) {
#pragma unroll
    for (int n = 0; n < 8; ++n) {
      const int gc = col0 + n * 16 + lr;
      const float bia = bias[gc];
#pragma unroll
      for (int j = 0; j < 4; ++j) {
        const int gr = row0 + wid * 32 + m * 16 + lk * 4 + j;
        hpre[(long)gr * DALL + gc] = __float2bfloat16(acc[m][n][j] + bia);
      }
    }
  }
}

// ---------------- LayerNorm + exact GELU, bf16 in -> bf16 out (r7/r11) -----
__global__ __launch_bounds__(256)
void ln_gelu_kernel(const bf16* __restrict__ h, const float* __restrict__ g,
                    const float* __restrict__ bb, bf16* __restrict__ h2) {
  const int row = blockIdx.x, tid = threadIdx.x;
  const bf16* x = h + (long)row * DALL;
  float v[14];
  float s1 = 0.f, s2 = 0.f;
#pragma unroll
  for (int i = 0; i < 14; ++i) {
    v[i] = __bfloat162float(x[i * 256 + tid]);
    s1 += v[i];
    s2 += v[i] * v[i];
  }
#pragma unroll
  for (int m = 32; m; m >>= 1) {
    s1 += __shfl_xor(s1, m);
    s2 += __shfl_xor(s2, m);
  }
  __shared__ float r1[4], r2[4];
  const int wid = tid >> 6, lane = tid & 63;
  if (lane == 0) {
    r1[wid] = s1;
    r2[wid] = s2;
  }
  __syncthreads();
  s1 = r1[0] + r1[1] + r1[2] + r1[3];
  s2 = r2[0] + r2[1] + r2[2] + r2[3];
  const float mean = s1 * (1.f / DALL);
  const float var = s2 * (1.f / DALL) - mean * mean;
  const float rstd = rsqrtf(var + 1e-5f);
#pragma unroll
  for (int i = 0; i < 14; ++i) {
    const int c = i * 256 + tid;
    const float y = (v[i] - mean) * rstd * g[c] + bb[c];
    const float ge = 0.5f * y * (1.f + erff(y * 0.7071067811865475f));
    h2[(long)row * DALL + c] = __float2bfloat16(ge);
  }
}

// ---------------- per-pair GEMM (K=256, BK=64 swizzled) + LN (r7/r11) ------
__global__ __launch_bounds__(256)
void pair_final(const bf16* __restrict__ psb, const bf16* __restrict__ fusedb,
                const bf16* __restrict__ pwT, const float* __restrict__ pb,
                const float* __restrict__ lng, const float* __restrict__ lnb,
                float* __restrict__ out) {
  __shared__ __align__(16) bf16 sA[128 * 64];
  __shared__ __align__(16) bf16 sB[128 * 64];
  const int tid = threadIdx.x, wid = tid >> 6, lane = tid & 63;
  const int lr = lane & 15, lk = lane >> 4;
  const int p = blockIdx.y, row0 = blockIdx.x * 128;
  const int srl = lane >> 3;
  const int sgl = (lane & 7) ^ srl;
  const int sx = lr & 7;
  const bf16* pwp = pwT + (long)p * (PDIM * MDIM);

  f32x4 acc[2][8];
  const f32x4 zero = {0.f, 0.f, 0.f, 0.f};
#pragma unroll
  for (int m = 0; m < 2; ++m)
#pragma unroll
    for (int n = 0; n < 8; ++n) acc[m][n] = zero;

  for (int kt = 0; kt < 4; ++kt) {
    __syncthreads();
    const bf16* Asrc = (kt < 2) ? psb : fusedb;
    const int acol = p * PDIM + (kt & 1) * 64;
#pragma unroll
    for (int i = 0; i < 4; ++i) {
      const int r = i * 32 + wid * 8 + srl;
      async_copy16((char*)sA + i * 4096 + wid * 1024,
                   Asrc + (long)(row0 + r) * DALL + acol + sgl * 8);
      async_copy16((char*)sB + i * 4096 + wid * 1024,
                   pwp + (long)r * MDIM + kt * 64 + sgl * 8);
    }
    __syncthreads();
#pragma unroll
    for (int kk = 0; kk < 2; ++kk) {
      bf16x8 a0[2], b0[8];
      const int gb = (((kk << 2) | lk) ^ sx) << 4;
#pragma unroll
      for (int m = 0; m < 2; ++m)
        a0[m] = *(const bf16x8*)((const char*)sA + (wid * 32 + m * 16 + lr) * 128 + gb);
#pragma unroll
      for (int n = 0; n < 8; ++n)
        b0[n] = *(const bf16x8*)((const char*)sB + (n * 16 + lr) * 128 + gb);
#pragma unroll
      for (int m = 0; m < 2; ++m)
#pragma unroll
        for (int n = 0; n < 8; ++n)
          acc[m][n] = __builtin_amdgcn_mfma_f32_16x16x32_bf16(
              a0[m], b0[n], acc[m][n], 0, 0, 0);
    }
  }
  float g_[8], b_[8], pb_[8];
#pragma unroll
  for (int n = 0; n < 8; ++n) {
    const int c = n * 16 + lr;
    g_[n] = lng[p * PDIM + c];
    b_[n] = lnb[p * PDIM + c];
    pb_[n] = pb[p * PDIM + c];
  }
#pragma unroll
  for (int m = 0; m < 2; ++m) {
#pragma unroll
    for (int j = 0; j < 4; ++j) {
      float vv[8];
      float s1 = 0.f, s2 = 0.f;
#pragma unroll
      for (int n = 0; n < 8; ++n) {
        vv[n] = acc[m][n][j] + pb_[n];
        s1 += vv[n];
        s2 += vv[n] * vv[n];
      }
#pragma unroll
      for (int msk = 1; msk <= 8; msk <<= 1) {
        s1 += __shfl_xor(s1, msk);
        s2 += __shfl_xor(s2, msk);
      }
      const float mean = s1 * (1.f / 128.f);
      const float var = s2 * (1.f / 128.f) - mean * mean;
      const float rstd = rsqrtf(var + 1e-5f);
      const int gr = row0 + wid * 32 + m * 16 + lk * 4 + j;
      float* orow = out + ((long)gr * NPAIR + p) * PDIM;
#pragma unroll
      for (int n = 0; n < 8; ++n)
        orow[n * 16 + lr] = (vv[n] - mean) * rstd * g_[n] + b_[n];
    }
  }
}

// ---------------------------------------------------------------------------
extern "C" void kernel_launch(void* const* d_in, const int* in_sizes, int n_in,
                              void* d_out, int out_size, void* d_ws, size_t ws_size,
                              hipStream_t stream) {
  (void)in_sizes; (void)n_in; (void)out_size; (void)ws_size;
  const float* ps   = (const float*)d_in[0];
  const float* mac  = (const float*)d_in[1];
  const float* pkey = (const float*)d_in[2];
  const float* pval = (const float*)d_in[3];
  const float* mkey = (const float*)d_in[4];
  const float* mval = (const float*)d_in[5];
  const float* w1   = (const float*)d_in[6];
  const float* b1   = (const float*)d_in[7];
  const float* lng1 = (const float*)d_in[8];
  const float* lnb1 = (const float*)d_in[9];
  const float* w2   = (const float*)d_in[10];
  const float* b2   = (const float*)d_in[11];
  const float* pw   = (const float*)d_in[12];
  const float* pb   = (const float*)d_in[13];
  const float* plng = (const float*)d_in[14];
  const float* plnb = (const float*)d_in[15];
  float* out = (float*)d_out;

  char* w = (char*)d_ws;
  size_t off = 0;
  auto carve = [&](size_t bytes) {
    char* pp = w + off;
    off += (bytes + 255) & ~(size_t)255;
    return pp;
  };
  bf16* psb   = (bf16*)carve((size_t)B_SZ * DALL * 2);
  bf16* w2t   = (bf16*)carve((size_t)(DALL + 32) * DALL * 2);  // +32 pad rows
  bf16* pvb   = (bf16*)carve((size_t)NSLOT * DALL * 2);
  bf16* mvb   = (bf16*)carve((size_t)NSLOT * DALL * 2);
  bf16* pwTb  = (bf16*)carve((size_t)NPAIR * PDIM * MDIM * 2);
  bf16* att   = (bf16*)carve((size_t)B_SZ * 128 * 2);
  bf16* cvt   = (bf16*)carve((size_t)DALL * 128 * 2);
  float* part = (float*)carve((size_t)KS2 * DALL * 64 * 4);    // 29.4 MB
  bf16* hpreb = (bf16*)carve((size_t)B_SZ * DALL * 2);
  bf16* h2    = (bf16*)carve((size_t)B_SZ * DALL * 2);
  bf16* fusedb = hpreb;  // alias: hpreb last read by ln_gelu

  // merged: vals (224) + pw T (896) + w2 T (12544) + prep (4096) = 17760
  all_conv<<<dim3(17760), 256, 0, stream>>>(pval, mval, pvb, mvb, pw, pwTb,
                                            w2, w2t, ps, mac, pkey, mkey, psb, att);
  precompute_direct<<<dim3(DALL / 256, KS2), 256, 0, stream>>>(w1, pvb, mvb, part);
  reduce_cvt<<<dim3(DALL * 128 / 1024), 256, 0, stream>>>(part, cvt);
  gemm_thin<<<dim3(DALL / 128, B_SZ / 128), 256, 0, stream>>>(att, cvt, hpreb, b1);
  ln_gelu_kernel<<<dim3(B_SZ), 256, 0, stream>>>(hpreb, lng1, lnb1, h2);
  gemm224<<<dim3(256), 512, 0, stream>>>(h2, w2t, fusedb, b2);
  pair_final<<<dim3(B_SZ / 128, NPAIR), 256, 0, stream>>>(
      psb, fusedb, pwTb, pb, plng, plnb, out);
}